// Round 4
// baseline (4139.931 us; speedup 1.0000x reference)
//
#include <hip/hip_runtime.h>
#include <hip/hip_bf16.h>

// LSTM trajectory predictor, Round 3: deep-pipelined MFMA cells.
// 4 LDS buffers (BK=32), stage-2-ahead, counted s_waitcnt vmcnt(16) (never
// drain to 0 in the main loop), raw s_barrier. bf16 hi/lo 3-product split.

#define HDIM 512
#define BDIM 2048
#define T_HIST 50
#define T_FUT 30

typedef __attribute__((ext_vector_type(8))) short short8;
typedef __attribute__((ext_vector_type(4))) float f32x4;

#define AS1(p) ((const __attribute__((address_space(1))) void*)(p))
#define AS3(p) ((__attribute__((address_space(3))) void*)(p))

__device__ __forceinline__ ushort f2bf(float f) {
    union { float f; unsigned u; } v; v.f = f;
    unsigned r = v.u + 0x7fff + ((v.u >> 16) & 1);   // RNE
    return (ushort)(r >> 16);
}
__device__ __forceinline__ float bf2f(ushort h) {
    union { unsigned u; float f; } v; v.u = ((unsigned)h) << 16;
    return v.f;
}

// Region layout (128 rows x 32 k, 16B slots, 4 slots/row):
// logical (row, slot) -> linear q = row>>1, t = ((row&1)<<2)|slot,
// phys = q*8 + (t ^ (q&7)).  Bijective; a frag read (16 rows x 4 slots)
// covers 8 full 128B bank-rows -> conflict-free ds_read_b128.
__device__ __forceinline__ int swz(int row, int slot) {
    int q = row >> 1;
    int t = ((row & 1) << 2) | slot;
    return q * 8 + (t ^ (q & 7));
}

// ---- weight prep: fp32 [2048][512] -> bf16 hi/lo [2048][512], rows permuted.
// input row = g*512 + u ; output row rp = (u>>5)*128 + ((u>>4)&1)*64 + g*16 + (u&15)
struct SplitSrc { const float* src[6]; };

__global__ __launch_bounds__(256) void split_weights(SplitSrc s, ushort* __restrict__ hi,
                                                     ushort* __restrict__ lo) {
    int row = blockIdx.x;             // g*512 + u
    int j = blockIdx.y;               // matrix index
    int g = row >> 9, u = row & 511;
    int rp = (u >> 5) * 128 + ((u >> 4) & 1) * 64 + g * 16 + (u & 15);
    const float* S = s.src[j] + (size_t)row * HDIM;
    ushort* H = hi + ((size_t)j * 2048 + rp) * HDIM;
    ushort* L = lo + ((size_t)j * 2048 + rp) * HDIM;
    for (int k = threadIdx.x; k < HDIM; k += 256) {
        float w = S[k];
        ushort hb = f2bf(w);
        H[k] = hb;
        L[k] = f2bf(w - bf2f(hb));
    }
}

// ---- fused LSTM cell ----
// Block 128m x 128n (32 units x 4 gates), 4 waves 2x2, wave tile 64x64
// (4 m-frags x 4 gate-frags of 16x16x32 bf16 MFMA).
// Chunks of K=32; regions per buffer: A_hi, A_lo, B_hi, B_lo (8KB each).
__global__ __launch_bounds__(256) void lstm_cell_mfma(
    const ushort* __restrict__ A1hi, const ushort* __restrict__ A1lo,
    const ushort* __restrict__ W1hi, const ushort* __restrict__ W1lo,
    const ushort* __restrict__ A2hi, const ushort* __restrict__ A2lo,
    const ushort* __restrict__ W2hi, const ushort* __restrict__ W2lo,
    int np,
    const float* __restrict__ x, int x_stride, int Kx, const float* __restrict__ Wx,
    const float* __restrict__ bih, const float* __restrict__ bhh,
    float* __restrict__ c_state, ushort* __restrict__ h_hi, ushort* __restrict__ h_lo)
{
    // 4 buffers x 32KB = 128KB. Buffer: A_hi @0, A_lo @4096, B_hi @8192,
    // B_lo @12288 (ushort offsets), each 512 slots x 16B.
    __shared__ __align__(16) ushort lds[4 * 16384];

    const int tid = threadIdx.x;
    const int w = tid >> 6, l = tid & 63;
    const int wm = w >> 1, wn = w & 1;
    const int lrow = l & 15, lk = l >> 4;

    // XCD-chunked bijective swizzle (256 blocks, 8 XCDs: 4bx x 8by per XCD)
    int id = blockIdx.y * 16 + blockIdx.x;
    int xcd = id & 7, rr = id >> 3;
    int bx = (xcd & 3) * 4 + (rr & 3);
    int by = (xcd >> 2) * 8 + (rr >> 2);
    const int m0 = by * 128;
    const int n0 = bx * 128;
    const int u  = bx * 32 + wn * 16 + lrow;   // global hidden unit

    f32x4 acc[4][4];   // [m-frag][gate]

    // ---- bias init + tiny-K x prologue FIRST (their vmem waits must not
    // drain the staging queue issued below) ----
    #pragma unroll
    for (int g = 0; g < 4; ++g) {
        float b = bih[g * HDIM + u] + bhh[g * HDIM + u];
        f32x4 bv = {b, b, b, b};
        #pragma unroll
        for (int fm = 0; fm < 4; ++fm) acc[fm][g] = bv;
    }
    if (Kx > 0) {
        for (int kx = 0; kx < Kx; ++kx) {
            float wv[4];
            #pragma unroll
            for (int g = 0; g < 4; ++g) wv[g] = Wx[(size_t)(g * HDIM + u) * Kx + kx];
            #pragma unroll
            for (int fm = 0; fm < 4; ++fm)
                #pragma unroll
                for (int r = 0; r < 4; ++r) {
                    int m = m0 + wm * 64 + fm * 16 + lk * 4 + r;
                    float xv = x[(size_t)m * x_stride + kx];
                    #pragma unroll
                    for (int g = 0; g < 4; ++g) acc[fm][g][r] += xv * wv[g];
                }
        }
    }

    // ---- staging: 8 global_load_lds per wave per chunk ----
    auto STAGE = [&](int t) {
        int buf = t & 3;
        int p = t >> 4;                 // 16 chunks per (A,W) pair
        int kc = (t & 15) * 32;
        const ushort* Ah = p ? A2hi : A1hi;
        const ushort* Al = p ? A2lo : A1lo;
        const ushort* Bh = p ? W2hi : W1hi;
        const ushort* Bl = p ? W2lo : W1lo;
        ushort* base = &lds[buf * 16384];
        #pragma unroll
        for (int it = 0; it < 2; ++it) {
            int db = (w * 2 + it) * 64;      // wave-uniform dest slot base
            int d = db + l;                   // this lane's dest slot
            int q = d >> 3, tp = d & 7;
            int tl = tp ^ (q & 7);            // inverse swizzle -> logical
            int r = (q << 1) | (tl >> 2);
            int s = tl & 3;
            size_t go = (size_t)r * HDIM + kc + s * 8;
            __builtin_amdgcn_global_load_lds(AS1(Ah + (size_t)m0 * HDIM + go),
                                             AS3(base + db * 8), 16, 0, 0);
            __builtin_amdgcn_global_load_lds(AS1(Al + (size_t)m0 * HDIM + go),
                                             AS3(base + 4096 + db * 8), 16, 0, 0);
            __builtin_amdgcn_global_load_lds(AS1(Bh + (size_t)n0 * HDIM + go),
                                             AS3(base + 8192 + db * 8), 16, 0, 0);
            __builtin_amdgcn_global_load_lds(AS1(Bl + (size_t)n0 * HDIM + go),
                                             AS3(base + 12288 + db * 8), 16, 0, 0);
        }
    };

    const int nch = np * 16;
    STAGE(0);
    STAGE(1);

    // ---- main loop: stage t+2, keep 2 chunks in flight (vmcnt(16)) ----
    for (int t = 0; t < nch; ++t) {
        if (t + 2 < nch) {
            STAGE(t + 2);
            asm volatile("s_waitcnt vmcnt(16)" ::: "memory");  // chunk t done
        } else if (t + 1 < nch) {
            asm volatile("s_waitcnt vmcnt(8)" ::: "memory");
        } else {
            asm volatile("s_waitcnt vmcnt(0)" ::: "memory");
        }
        __builtin_amdgcn_s_barrier();          // all waves' chunk-t stores done
        __builtin_amdgcn_sched_barrier(0);     // no hoisting of reads above

        ushort* base = &lds[(t & 3) * 16384];
        short8 ah[4], al[4], bh[4], bl[4];
        #pragma unroll
        for (int fm = 0; fm < 4; ++fm) {
            int row = wm * 64 + fm * 16 + lrow;
            int off = swz(row, lk) * 8;
            ah[fm] = *(const short8*)(base + off);
            al[fm] = *(const short8*)(base + 4096 + off);
        }
        #pragma unroll
        for (int g = 0; g < 4; ++g) {
            int row = wn * 64 + g * 16 + lrow;
            int off = swz(row, lk) * 8;
            bh[g] = *(const short8*)(base + 8192 + off);
            bl[g] = *(const short8*)(base + 12288 + off);
        }
        #pragma unroll
        for (int fm = 0; fm < 4; ++fm)
            #pragma unroll
            for (int g = 0; g < 4; ++g)
                acc[fm][g] = __builtin_amdgcn_mfma_f32_16x16x32_bf16(
                    ah[fm], bh[g], acc[fm][g], 0, 0, 0);
        #pragma unroll
        for (int fm = 0; fm < 4; ++fm)
            #pragma unroll
            for (int g = 0; g < 4; ++g)
                acc[fm][g] = __builtin_amdgcn_mfma_f32_16x16x32_bf16(
                    al[fm], bh[g], acc[fm][g], 0, 0, 0);
        #pragma unroll
        for (int fm = 0; fm < 4; ++fm)
            #pragma unroll
            for (int g = 0; g < 4; ++g)
                acc[fm][g] = __builtin_amdgcn_mfma_f32_16x16x32_bf16(
                    ah[fm], bl[g], acc[fm][g], 0, 0, 0);
    }

    // ---- epilogue: gates + state update. Thread owns 16 rows x 1 unit. ----
    #pragma unroll
    for (int fm = 0; fm < 4; ++fm)
        #pragma unroll
        for (int r = 0; r < 4; ++r) {
            int m = m0 + wm * 64 + fm * 16 + lk * 4 + r;
            size_t idx = (size_t)m * HDIM + u;
            float zi = acc[fm][0][r], zf = acc[fm][1][r];
            float zg = acc[fm][2][r], zo = acc[fm][3][r];
            float ig = 1.f / (1.f + __expf(-zi));
            float fg = 1.f / (1.f + __expf(-zf));
            float gg = 2.f / (1.f + __expf(-2.f * zg)) - 1.f;
            float og = 1.f / (1.f + __expf(-zo));
            float cn = fg * c_state[idx] + ig * gg;
            float hn = og * (2.f / (1.f + __expf(-2.f * cn)) - 1.f);
            c_state[idx] = cn;
            ushort hb = f2bf(hn);
            h_hi[idx] = hb;
            h_lo[idx] = f2bf(hn - bf2f(hb));
        }
}

// ---- output head: pred = (h_hi+h_lo) @ out_W^T + out_b, one wave per row ----
__global__ __launch_bounds__(256) void head_kernel(
    const ushort* __restrict__ hhi, const ushort* __restrict__ hlo,
    const float* __restrict__ Wout, const float* __restrict__ bout,
    float* __restrict__ out, float* __restrict__ xbuf, int t)
{
    int wave = (blockIdx.x * 256 + threadIdx.x) >> 6;
    int lane = threadIdx.x & 63;
    const ushort* hr = hhi + (size_t)wave * HDIM;
    const ushort* lr = hlo + (size_t)wave * HDIM;
    float s0 = 0.f, s1 = 0.f;
    #pragma unroll
    for (int k = lane; k < HDIM; k += 64) {
        float hv = bf2f(hr[k]) + bf2f(lr[k]);
        s0 += hv * Wout[k];
        s1 += hv * Wout[HDIM + k];
    }
    #pragma unroll
    for (int off = 32; off > 0; off >>= 1) {
        s0 += __shfl_down(s0, off);
        s1 += __shfl_down(s1, off);
    }
    if (lane == 0) {
        float p0 = s0 + bout[0], p1 = s1 + bout[1];
        out[(size_t)wave * (T_FUT * 2) + t * 2 + 0] = p0;
        out[(size_t)wave * (T_FUT * 2) + t * 2 + 1] = p1;
        xbuf[wave * 2 + 0] = p0;
        xbuf[wave * 2 + 1] = p1;
    }
}

extern "C" void kernel_launch(void* const* d_in, const int* in_sizes, int n_in,
                              void* d_out, int out_size, void* d_ws, size_t ws_size,
                              hipStream_t stream) {
    const float* history = (const float*)d_in[0];
    const float* eWih0 = (const float*)d_in[2];
    const float* eWhh0 = (const float*)d_in[3];
    const float* ebih0 = (const float*)d_in[4];
    const float* ebhh0 = (const float*)d_in[5];
    const float* eWih1 = (const float*)d_in[6];
    const float* eWhh1 = (const float*)d_in[7];
    const float* ebih1 = (const float*)d_in[8];
    const float* ebhh1 = (const float*)d_in[9];
    const float* dWih0 = (const float*)d_in[10];
    const float* dWhh0 = (const float*)d_in[11];
    const float* dbih0 = (const float*)d_in[12];
    const float* dbhh0 = (const float*)d_in[13];
    const float* dWih1 = (const float*)d_in[14];
    const float* dWhh1 = (const float*)d_in[15];
    const float* dbih1 = (const float*)d_in[16];
    const float* dbhh1 = (const float*)d_in[17];
    const float* outW  = (const float*)d_in[18];
    const float* outb  = (const float*)d_in[19];
    float* out = (float*)d_out;

    // ---- workspace layout ----
    const size_t M = (size_t)2048 * 512;
    ushort* whi = (ushort*)d_ws;           // 6 split-hi weight matrices
    ushort* wlo = whi + 6 * M;             // 6 split-lo
    ushort* hb  = wlo + 6 * M;             // 8 h buffers (hi/lo x 2 layers x dbuf)
    float*  c0  = (float*)(hb + 8 * M);
    float*  c1  = c0 + M;
    float*  xbuf = c1 + M;                 // [B,2] decoder feedback

    ushort* h0a_hi = hb + 0 * M; ushort* h0a_lo = hb + 1 * M;
    ushort* h0b_hi = hb + 2 * M; ushort* h0b_lo = hb + 3 * M;
    ushort* h1a_hi = hb + 4 * M; ushort* h1a_lo = hb + 5 * M;
    ushort* h1b_hi = hb + 6 * M; ushort* h1b_lo = hb + 7 * M;

    hipMemsetAsync(h0a_hi, 0, 2 * M * sizeof(ushort), stream);
    hipMemsetAsync(h1a_hi, 0, 2 * M * sizeof(ushort), stream);
    hipMemsetAsync(c0, 0, 2 * M * sizeof(float), stream);
    hipMemsetAsync(xbuf, 0, BDIM * 2 * sizeof(float), stream);

    SplitSrc ss;
    ss.src[0] = eWhh0; ss.src[1] = eWih1; ss.src[2] = eWhh1;
    ss.src[3] = dWhh0; ss.src[4] = dWih1; ss.src[5] = dWhh1;
    split_weights<<<dim3(2048, 6), 256, 0, stream>>>(ss, whi, wlo);

    #define WHI(j) (whi + (size_t)(j) * M)
    #define WLO(j) (wlo + (size_t)(j) * M)

    dim3 cgrid(16, 16);   // (N/128, B/128) = 256 blocks = 1/CU
    dim3 blk(256);

    for (int s = 0; s < T_HIST + T_FUT; ++s) {
        ushort* h0r_hi = (s & 1) ? h0b_hi : h0a_hi;
        ushort* h0r_lo = (s & 1) ? h0b_lo : h0a_lo;
        ushort* h0w_hi = (s & 1) ? h0a_hi : h0b_hi;
        ushort* h0w_lo = (s & 1) ? h0a_lo : h0b_lo;
        ushort* h1r_hi = (s & 1) ? h1b_hi : h1a_hi;
        ushort* h1r_lo = (s & 1) ? h1b_lo : h1a_lo;
        ushort* h1w_hi = (s & 1) ? h1a_hi : h1b_hi;
        ushort* h1w_lo = (s & 1) ? h1a_lo : h1b_lo;

        if (s < T_HIST) {
            lstm_cell_mfma<<<cgrid, blk, 0, stream>>>(
                h0r_hi, h0r_lo, WHI(0), WLO(0),
                nullptr, nullptr, nullptr, nullptr, 1,
                history + s * 5, T_HIST * 5, 5, eWih0,
                ebih0, ebhh0, c0, h0w_hi, h0w_lo);
            lstm_cell_mfma<<<cgrid, blk, 0, stream>>>(
                h0w_hi, h0w_lo, WHI(1), WLO(1),
                h1r_hi, h1r_lo, WHI(2), WLO(2), 2,
                nullptr, 0, 0, nullptr,
                ebih1, ebhh1, c1, h1w_hi, h1w_lo);
        } else {
            lstm_cell_mfma<<<cgrid, blk, 0, stream>>>(
                h0r_hi, h0r_lo, WHI(3), WLO(3),
                nullptr, nullptr, nullptr, nullptr, 1,
                xbuf, 2, 2, dWih0,
                dbih0, dbhh0, c0, h0w_hi, h0w_lo);
            lstm_cell_mfma<<<cgrid, blk, 0, stream>>>(
                h0w_hi, h0w_lo, WHI(4), WLO(4),
                h1r_hi, h1r_lo, WHI(5), WLO(5), 2,
                nullptr, 0, 0, nullptr,
                dbih1, dbhh1, c1, h1w_hi, h1w_lo);
            head_kernel<<<512, blk, 0, stream>>>(h1w_hi, h1w_lo, outW, outb,
                                                 out, xbuf, s - T_HIST);
        }
    }
    #undef WHI
    #undef WLO
}

// Round 5
// 3770.959 us; speedup vs baseline: 1.0978x; 1.0978x over previous
//
#include <hip/hip_runtime.h>
#include <hip/hip_bf16.h>

// LSTM trajectory predictor, Round 5: bf16 hi/lo split MFMA cells.
// BK=32, 2 LDS buffers (64KB -> 2 blocks/CU), plain 2-phase loop (one
// __syncthreads per chunk), and PAIRED dispatches: L1(s) || L0(s+1) run as
// one 512-block launch for cross-block latency hiding (2 waves/SIMD).

#define HDIM 512
#define BDIM 2048
#define T_HIST 50
#define T_FUT 30

typedef __attribute__((ext_vector_type(8))) short short8;
typedef __attribute__((ext_vector_type(4))) float f32x4;

#define AS1(p) ((const __attribute__((address_space(1))) void*)(p))
#define AS3(p) ((__attribute__((address_space(3))) void*)(p))

__device__ __forceinline__ ushort f2bf(float f) {
    union { float f; unsigned u; } v; v.f = f;
    unsigned r = v.u + 0x7fff + ((v.u >> 16) & 1);   // RNE
    return (ushort)(r >> 16);
}
__device__ __forceinline__ float bf2f(ushort h) {
    union { unsigned u; float f; } v; v.u = ((unsigned)h) << 16;
    return v.f;
}

// Region layout (128 rows x 32 k, 16B slots, 4 slots/row):
// q = row>>1, t = ((row&1)<<2)|slot, phys = q*8 + (t ^ (q&7)).
// Bijective; frag reads (16 rows x 4 slots) hit all 32 banks conflict-free.
__device__ __forceinline__ int swz(int row, int slot) {
    int q = row >> 1;
    int t = ((row & 1) << 2) | slot;
    return q * 8 + (t ^ (q & 7));
}

// ---- weight prep: fp32 [2048][512] -> bf16 hi/lo, rows permuted so a
// block's 128 rows = 32 units x 4 gates (gate index in bits [4:5] of rp).
// input row = g*512 + u ; rp = (u>>5)*128 + ((u>>4)&1)*64 + g*16 + (u&15)
struct SplitSrc { const float* src[6]; };

__global__ __launch_bounds__(256) void split_weights(SplitSrc s, ushort* __restrict__ hi,
                                                     ushort* __restrict__ lo) {
    int row = blockIdx.x;             // g*512 + u
    int j = blockIdx.y;               // matrix index
    int g = row >> 9, u = row & 511;
    int rp = (u >> 5) * 128 + ((u >> 4) & 1) * 64 + g * 16 + (u & 15);
    const float* S = s.src[j] + (size_t)row * HDIM;
    ushort* H = hi + ((size_t)j * 2048 + rp) * HDIM;
    ushort* L = lo + ((size_t)j * 2048 + rp) * HDIM;
    for (int k = threadIdx.x; k < HDIM; k += 256) {
        float w = S[k];
        ushort hb = f2bf(w);
        H[k] = hb;
        L[k] = f2bf(w - bf2f(hb));
    }
}

// ---- cell descriptor (one LSTM cell = one 2048x2048xK GEMM + gates) ----
struct CellDesc {
    const ushort *A1h, *A1l, *W1h, *W1l;
    const ushort *A2h, *A2l, *W2h, *W2l;
    const float *x; const float *Wx;
    const float *bih, *bhh;
    float* c; ushort *hh; ushort *hl;
    int np, xs, Kx;
};

// ---- fused LSTM cell(s): blocks [0,256) run dA, [256,512) run dB ----
// Block tile 128m x 128n (32 units x 4 gates), 4 waves 2x2, wave tile 64x64
// = 4 m-frags x 4 gate-frags of mfma_f32_16x16x32_bf16, 3-product split.
__global__ __launch_bounds__(256, 2) void lstm_cells(CellDesc dA, CellDesc dB) {
    // 2 buffers x 32KB. Regions (ushort offs): A_hi @0, A_lo @4096,
    // B_hi @8192, B_lo @12288; each 512 slots x 16B, swizzled.
    __shared__ __align__(16) ushort lds[2 * 16384];

    const CellDesc d = (blockIdx.x >> 8) ? dB : dA;

    const int tid = threadIdx.x;
    const int w = tid >> 6, l = tid & 63;
    const int wm = w >> 1, wn = w & 1;
    const int lrow = l & 15, lk = l >> 4;

    // XCD-chunked bijective swizzle within each cell's 256 blocks
    int id = blockIdx.x & 255;
    int xcd = id & 7, rr = id >> 3;
    int bx = (xcd & 3) * 4 + (rr & 3);
    int by = (xcd >> 2) * 8 + (rr >> 2);
    const int m0 = by * 128;
    const int n0 = bx * 128;
    const int u  = bx * 32 + wn * 16 + lrow;   // global hidden unit

    f32x4 acc[4][4];   // [m-frag][gate]

    // ---- bias + tiny-K x prologue FIRST (their vmem waits must not drain
    // the staging queue issued below) ----
    #pragma unroll
    for (int g = 0; g < 4; ++g) {
        float b = d.bih[g * HDIM + u] + d.bhh[g * HDIM + u];
        f32x4 bv = {b, b, b, b};
        #pragma unroll
        for (int fm = 0; fm < 4; ++fm) acc[fm][g] = bv;
    }
    if (d.Kx > 0) {
        for (int kx = 0; kx < d.Kx; ++kx) {
            float wv[4];
            #pragma unroll
            for (int g = 0; g < 4; ++g) wv[g] = d.Wx[(size_t)(g * HDIM + u) * d.Kx + kx];
            #pragma unroll
            for (int fm = 0; fm < 4; ++fm)
                #pragma unroll
                for (int r = 0; r < 4; ++r) {
                    int m = m0 + wm * 64 + fm * 16 + lk * 4 + r;
                    float xv = d.x[(size_t)m * d.xs + kx];
                    #pragma unroll
                    for (int g = 0; g < 4; ++g) acc[fm][g][r] += xv * wv[g];
                }
        }
    }

    // ---- staging: 8 global_load_lds (16B) per wave per chunk ----
    auto STAGE = [&](int t) {
        int buf = t & 1;
        int p = t >> 4;                 // 16 chunks per (A,W) pair
        int kc = (t & 15) * 32;
        const ushort* Ah = p ? d.A2h : d.A1h;
        const ushort* Al = p ? d.A2l : d.A1l;
        const ushort* Bh = p ? d.W2h : d.W1h;
        const ushort* Bl = p ? d.W2l : d.W1l;
        ushort* base = &lds[buf * 16384];
        #pragma unroll
        for (int it = 0; it < 2; ++it) {
            int db = (w * 2 + it) * 64;       // wave-uniform dest slot base
            int dd = db + l;                  // this lane's dest slot
            int q = dd >> 3, tp = dd & 7;
            int tl = tp ^ (q & 7);            // inverse swizzle -> logical
            int r = (q << 1) | (tl >> 2);
            int s = tl & 3;
            size_t go = (size_t)r * HDIM + kc + s * 8;
            __builtin_amdgcn_global_load_lds(AS1(Ah + (size_t)m0 * HDIM + go),
                                             AS3(base + db * 8), 16, 0, 0);
            __builtin_amdgcn_global_load_lds(AS1(Al + (size_t)m0 * HDIM + go),
                                             AS3(base + 4096 + db * 8), 16, 0, 0);
            __builtin_amdgcn_global_load_lds(AS1(Bh + (size_t)n0 * HDIM + go),
                                             AS3(base + 8192 + db * 8), 16, 0, 0);
            __builtin_amdgcn_global_load_lds(AS1(Bl + (size_t)n0 * HDIM + go),
                                             AS3(base + 12288 + db * 8), 16, 0, 0);
        }
    };

    const int nch = d.np * 16;
    STAGE(0);

    // ---- main loop: one __syncthreads per chunk (drains vmcnt+lgkm);
    // stage t+1 into the other buffer while computing t. Cross-block TLP
    // (2 blocks/CU) hides the drain. ----
    for (int t = 0; t < nch; ++t) {
        __syncthreads();                 // STAGE(t) visible; prev reads done
        if (t + 1 < nch) STAGE(t + 1);
        ushort* base = &lds[(t & 1) * 16384];
        short8 ah[4], al[4], bh[4], bl[4];
        #pragma unroll
        for (int fm = 0; fm < 4; ++fm) {
            int row = wm * 64 + fm * 16 + lrow;
            int off = swz(row, lk) * 8;
            ah[fm] = *(const short8*)(base + off);
            al[fm] = *(const short8*)(base + 4096 + off);
        }
        #pragma unroll
        for (int g = 0; g < 4; ++g) {
            int row = wn * 64 + g * 16 + lrow;
            int off = swz(row, lk) * 8;
            bh[g] = *(const short8*)(base + 8192 + off);
            bl[g] = *(const short8*)(base + 12288 + off);
        }
        #pragma unroll
        for (int fm = 0; fm < 4; ++fm)
            #pragma unroll
            for (int g = 0; g < 4; ++g)
                acc[fm][g] = __builtin_amdgcn_mfma_f32_16x16x32_bf16(
                    ah[fm], bh[g], acc[fm][g], 0, 0, 0);
        #pragma unroll
        for (int fm = 0; fm < 4; ++fm)
            #pragma unroll
            for (int g = 0; g < 4; ++g)
                acc[fm][g] = __builtin_amdgcn_mfma_f32_16x16x32_bf16(
                    al[fm], bh[g], acc[fm][g], 0, 0, 0);
        #pragma unroll
        for (int fm = 0; fm < 4; ++fm)
            #pragma unroll
            for (int g = 0; g < 4; ++g)
                acc[fm][g] = __builtin_amdgcn_mfma_f32_16x16x32_bf16(
                    ah[fm], bl[g], acc[fm][g], 0, 0, 0);
    }

    // ---- epilogue: gates + state update. Thread owns 16 rows x 1 unit. ----
    #pragma unroll
    for (int fm = 0; fm < 4; ++fm)
        #pragma unroll
        for (int r = 0; r < 4; ++r) {
            int m = m0 + wm * 64 + fm * 16 + lk * 4 + r;
            size_t idx = (size_t)m * HDIM + u;
            float zi = acc[fm][0][r], zf = acc[fm][1][r];
            float zg = acc[fm][2][r], zo = acc[fm][3][r];
            float ig = 1.f / (1.f + __expf(-zi));
            float fg = 1.f / (1.f + __expf(-zf));
            float gg = 2.f / (1.f + __expf(-2.f * zg)) - 1.f;
            float og = 1.f / (1.f + __expf(-zo));
            float cn = fg * d.c[idx] + ig * gg;
            float hn = og * (2.f / (1.f + __expf(-2.f * cn)) - 1.f);
            d.c[idx] = cn;
            ushort hb = f2bf(hn);
            d.hh[idx] = hb;
            d.hl[idx] = f2bf(hn - bf2f(hb));
        }
}

// ---- output head: pred = (h_hi+h_lo) @ out_W^T + out_b, one wave per row ----
__global__ __launch_bounds__(256) void head_kernel(
    const ushort* __restrict__ hhi, const ushort* __restrict__ hlo,
    const float* __restrict__ Wout, const float* __restrict__ bout,
    float* __restrict__ out, float* __restrict__ xbuf, int t)
{
    int wave = (blockIdx.x * 256 + threadIdx.x) >> 6;
    int lane = threadIdx.x & 63;
    const ushort* hr = hhi + (size_t)wave * HDIM;
    const ushort* lr = hlo + (size_t)wave * HDIM;
    float s0 = 0.f, s1 = 0.f;
    #pragma unroll
    for (int k = lane; k < HDIM; k += 64) {
        float hv = bf2f(hr[k]) + bf2f(lr[k]);
        s0 += hv * Wout[k];
        s1 += hv * Wout[HDIM + k];
    }
    #pragma unroll
    for (int off = 32; off > 0; off >>= 1) {
        s0 += __shfl_down(s0, off);
        s1 += __shfl_down(s1, off);
    }
    if (lane == 0) {
        float p0 = s0 + bout[0], p1 = s1 + bout[1];
        out[(size_t)wave * (T_FUT * 2) + t * 2 + 0] = p0;
        out[(size_t)wave * (T_FUT * 2) + t * 2 + 1] = p1;
        xbuf[wave * 2 + 0] = p0;
        xbuf[wave * 2 + 1] = p1;
    }
}

extern "C" void kernel_launch(void* const* d_in, const int* in_sizes, int n_in,
                              void* d_out, int out_size, void* d_ws, size_t ws_size,
                              hipStream_t stream) {
    const float* history = (const float*)d_in[0];
    const float* eWih0 = (const float*)d_in[2];
    const float* eWhh0 = (const float*)d_in[3];
    const float* ebih0 = (const float*)d_in[4];
    const float* ebhh0 = (const float*)d_in[5];
    const float* eWih1 = (const float*)d_in[6];
    const float* eWhh1 = (const float*)d_in[7];
    const float* ebih1 = (const float*)d_in[8];
    const float* ebhh1 = (const float*)d_in[9];
    const float* dWih0 = (const float*)d_in[10];
    const float* dWhh0 = (const float*)d_in[11];
    const float* dbih0 = (const float*)d_in[12];
    const float* dbhh0 = (const float*)d_in[13];
    const float* dWih1 = (const float*)d_in[14];
    const float* dWhh1 = (const float*)d_in[15];
    const float* dbih1 = (const float*)d_in[16];
    const float* dbhh1 = (const float*)d_in[17];
    const float* outW  = (const float*)d_in[18];
    const float* outb  = (const float*)d_in[19];
    float* out = (float*)d_out;

    // ---- workspace layout ----
    const size_t M = (size_t)2048 * 512;
    ushort* whi = (ushort*)d_ws;           // 6 split-hi weight matrices
    ushort* wlo = whi + 6 * M;             // 6 split-lo
    ushort* hb  = wlo + 6 * M;             // 8 h buffers (hi/lo x 2 layers x dbuf)
    float*  c0  = (float*)(hb + 8 * M);
    float*  c1  = c0 + M;
    float*  xbuf = c1 + M;                 // [B,2] decoder feedback

    ushort* h0a_hi = hb + 0 * M; ushort* h0a_lo = hb + 1 * M;
    ushort* h0b_hi = hb + 2 * M; ushort* h0b_lo = hb + 3 * M;
    ushort* h1a_hi = hb + 4 * M; ushort* h1a_lo = hb + 5 * M;
    ushort* h1b_hi = hb + 6 * M; ushort* h1b_lo = hb + 7 * M;

    hipMemsetAsync(h0a_hi, 0, 2 * M * sizeof(ushort), stream);
    hipMemsetAsync(h1a_hi, 0, 2 * M * sizeof(ushort), stream);
    hipMemsetAsync(c0, 0, 2 * M * sizeof(float), stream);
    hipMemsetAsync(xbuf, 0, BDIM * 2 * sizeof(float), stream);

    SplitSrc ss;
    ss.src[0] = eWhh0; ss.src[1] = eWih1; ss.src[2] = eWhh1;
    ss.src[3] = dWhh0; ss.src[4] = dWih1; ss.src[5] = dWhh1;
    split_weights<<<dim3(2048, 6), 256, 0, stream>>>(ss, whi, wlo);

    #define WHI(j) (whi + (size_t)(j) * M)
    #define WLO(j) (wlo + (size_t)(j) * M)

    // per-step buffer parity
    auto H0R_HI = [&](int s){ return (s & 1) ? h0b_hi : h0a_hi; };
    auto H0R_LO = [&](int s){ return (s & 1) ? h0b_lo : h0a_lo; };
    auto H0W_HI = [&](int s){ return (s & 1) ? h0a_hi : h0b_hi; };
    auto H0W_LO = [&](int s){ return (s & 1) ? h0a_lo : h0b_lo; };
    auto H1R_HI = [&](int s){ return (s & 1) ? h1b_hi : h1a_hi; };
    auto H1R_LO = [&](int s){ return (s & 1) ? h1b_lo : h1a_lo; };
    auto H1W_HI = [&](int s){ return (s & 1) ? h1a_hi : h1b_hi; };
    auto H1W_LO = [&](int s){ return (s & 1) ? h1a_lo : h1b_lo; };

    auto mkL0enc = [&](int s) {
        CellDesc d{};
        d.A1h = H0R_HI(s); d.A1l = H0R_LO(s); d.W1h = WHI(0); d.W1l = WLO(0);
        d.np = 1; d.x = history + s * 5; d.xs = T_HIST * 5; d.Kx = 5; d.Wx = eWih0;
        d.bih = ebih0; d.bhh = ebhh0; d.c = c0; d.hh = H0W_HI(s); d.hl = H0W_LO(s);
        return d;
    };
    auto mkL1enc = [&](int s) {
        CellDesc d{};
        d.A1h = H0W_HI(s); d.A1l = H0W_LO(s); d.W1h = WHI(1); d.W1l = WLO(1);
        d.A2h = H1R_HI(s); d.A2l = H1R_LO(s); d.W2h = WHI(2); d.W2l = WLO(2);
        d.np = 2; d.Kx = 0; d.xs = 0;
        d.bih = ebih1; d.bhh = ebhh1; d.c = c1; d.hh = H1W_HI(s); d.hl = H1W_LO(s);
        return d;
    };
    auto mkD0 = [&](int s) {
        CellDesc d{};
        d.A1h = H0R_HI(s); d.A1l = H0R_LO(s); d.W1h = WHI(3); d.W1l = WLO(3);
        d.np = 1; d.x = xbuf; d.xs = 2; d.Kx = 2; d.Wx = dWih0;
        d.bih = dbih0; d.bhh = dbhh0; d.c = c0; d.hh = H0W_HI(s); d.hl = H0W_LO(s);
        return d;
    };
    auto mkD1 = [&](int s) {
        CellDesc d{};
        d.A1h = H0W_HI(s); d.A1l = H0W_LO(s); d.W1h = WHI(4); d.W1l = WLO(4);
        d.A2h = H1R_HI(s); d.A2l = H1R_LO(s); d.W2h = WHI(5); d.W2l = WLO(5);
        d.np = 2; d.Kx = 0; d.xs = 0;
        d.bih = dbih1; d.bhh = dbhh1; d.c = c1; d.hh = H1W_HI(s); d.hl = H1W_LO(s);
        return d;
    };

    dim3 blk(256);

    // encoder step 0, layer 0 alone
    {
        CellDesc d = mkL0enc(0);
        lstm_cells<<<256, blk, 0, stream>>>(d, d);
    }
    // paired: [L1(s) || L0(s+1)], with the last pair feeding the decoder
    for (int s = 0; s < T_HIST; ++s) {
        CellDesc dL1 = mkL1enc(s);
        CellDesc dNx = (s + 1 < T_HIST) ? mkL0enc(s + 1) : mkD0(T_HIST);
        lstm_cells<<<512, blk, 0, stream>>>(dL1, dNx);
    }
    // decoder: D1(s) -> head(s) -> D0(s+1)
    for (int s = T_HIST; s < T_HIST + T_FUT; ++s) {
        CellDesc d1 = mkD1(s);
        lstm_cells<<<256, blk, 0, stream>>>(d1, d1);
        head_kernel<<<512, blk, 0, stream>>>(H1W_HI(s), H1W_LO(s), outW, outb,
                                             out, xbuf, s - T_HIST);
        if (s + 1 < T_HIST + T_FUT) {
            CellDesc d0 = mkD0(s + 1);
            lstm_cells<<<256, blk, 0, stream>>>(d0, d0);
        }
    }
    #undef WHI
    #undef WLO
}